// Round 1
// baseline (227.675 us; speedup 1.0000x reference)
//
#include <hip/hip_runtime.h>
#include <math.h>

// Problem constants (from setup_inputs): B=2, V=10000, N=16, CIN=128, COUT=64
#define V_CNT 10000
#define NB 16
#define TQ 16          // queries per block in fold_kernel
#define BQ_TOTAL 20000 // B*V
#define NCOL 100000    // B*V*5 output columns for the final GEMM

// ws float layout:
//   [0, 2880)        W45[d][kj]     (64 x 45)
//   [2880, 2925)     Wdir9[kj]      (45)
//   [2944, 3004)     FN[f*3+axis]   (20 x 3 face normals)
//   [8192, 8192+100000*48)  PsG[(qg*5+s)*48 + kj]  (K padded 45->48)
#define WS_W45   0
#define WS_WD9   2880
#define WS_FN    2944
#define WS_PSG   8192

// _FTC permutation table (runtime-indexed -> device constant memory)
__device__ __constant__ int FTC_d[20][5] = {
  {1,4,0,2,3},{2,0,1,4,3},{3,1,0,4,2},{4,2,0,3,1},{0,3,1,2,4},
  {3,2,0,4,1},{4,3,0,2,1},{0,4,1,2,3},{1,0,2,4,3},{2,1,0,4,3},
  {4,0,1,3,2},{0,1,2,3,4},{1,2,0,3,4},{2,3,0,1,4},{3,4,0,1,2},
  {1,3,0,2,4},{0,2,1,3,4},{4,1,0,3,2},{3,0,1,4,2},{2,4,0,1,3}};

// color of face f = _FTC[f][0] (compile-time folded in unrolled loops)
constexpr int COLF[20] = {1,2,3,4,0,3,4,0,1,2,4,0,1,2,3,1,0,4,3,2};

// w9[k][j] = w19[W9MAP[k][j]]  (the _build_kernel row construction)
constexpr int W9MAP[9][5] = {
  {0,1,2,2,2},{3,4,5,5,5},
  {9,10,11,12,13},{9,10,12,13,11},{9,10,13,11,12},
  {14,15,16,17,18},{14,15,17,18,16},{14,15,18,16,17},
  {6,7,8,8,8}};

__device__ __constant__ int FACES_d[20][3] = {
  {1,2,7},{1,3,7},{1,3,5},{1,4,5},{1,2,4},{2,7,8},{3,7,9},{3,5,11},{4,5,6},{2,4,10},
  {2,8,10},{7,8,9},{3,9,11},{5,6,11},{4,6,10},{0,8,10},{0,6,10},{0,6,11},{0,9,11},{0,8,9}};

#define PHI_F 1.61803398874989484820f
__device__ __constant__ float VS_d[12][3] = {
  {-1.f,PHI_F,0.f},{1.f,PHI_F,0.f},{-1.f,-PHI_F,0.f},{1.f,-PHI_F,0.f},
  {0.f,-1.f,PHI_F},{0.f,1.f,PHI_F},{0.f,-1.f,-PHI_F},{0.f,1.f,-PHI_F},
  {PHI_F,0.f,-1.f},{PHI_F,0.f,1.f},{-PHI_F,0.f,-1.f},{-PHI_F,0.f,1.f}};

__device__ __forceinline__ float fast_tanh(float x){
  // |x| <= 1 here (dot of unit vectors), no overflow concerns
  float e = __expf(2.0f * x);
  return 1.0f - 2.0f * __builtin_amdgcn_rcpf(e + 1.0f);
}

// ---------------------------------------------------------------------------
// Kernel 1: weight prep. Blocks 0..63: W45[d] = w9(sum_c W[d,c,:]).
//           Block 64: Wdir9 = w9(sum_c W_dir[c,:]) + face normals.
// ---------------------------------------------------------------------------
__global__ __launch_bounds__(128) void prep_kernel(const float* __restrict__ W,
                                                   const float* __restrict__ Wdir,
                                                   float* __restrict__ ws){
  __shared__ float buf[128][20];   // pad 19->20 to break bank stride
  __shared__ float w19s[19];
  int d = blockIdx.x;   // 0..64
  int c = threadIdx.x;  // 0..127  (one per CIN)

  const float* src = (d < 64) ? (W + ((size_t)d*128 + c)*19) : (Wdir + (size_t)c*19);
  #pragma unroll
  for (int tt = 0; tt < 19; ++tt) buf[c][tt] = src[tt];

  if (d == 64 && c < 20){
    float x=0.f, y=0.f, z=0.f;
    #pragma unroll
    for (int vv=0; vv<3; ++vv){
      int vi = FACES_d[c][vv];
      x += VS_d[vi][0]; y += VS_d[vi][1]; z += VS_d[vi][2];
    }
    float inv = rsqrtf(x*x + y*y + z*z);
    ws[WS_FN + c*3 + 0] = x*inv;
    ws[WS_FN + c*3 + 1] = y*inv;
    ws[WS_FN + c*3 + 2] = z*inv;
  }
  __syncthreads();

  if (c < 19){
    float s = 0.f;
    for (int i = 0; i < 128; ++i) s += buf[i][c];
    w19s[c] = s;
  }
  __syncthreads();

  if (c < 45){
    int k = c / 5, j = c % 5;
    float v = w19s[W9MAP[k][j]];
    ws[(d < 64) ? (WS_W45 + d*45 + c) : (WS_WD9 + c)] = v;
  }
}

// ---------------------------------------------------------------------------
// Kernel 2: per block: TQ=16 queries.
//  Phase A (256 threads = 16q x 16n): gather neighbor, normalize, 20 face
//          dots -> tanh -> 5 color sums  => de5s in LDS.
//  Phase B (320 threads = 16q x 20r): per (q,r) accumulate
//          P[kj] = sum_n relu(Wdir9[k].e) * e[j],  e[j]=de5[n][FTC[r][j]];
//          atomicAdd into Ps[q][color(r)][kj]  (4-way contention).
//  Store Ps (K padded to 48) to global scratch, coalesced.
// ---------------------------------------------------------------------------
__global__ __launch_bounds__(320) void fold_kernel(const int*   __restrict__ nbr,
                                                   const float* __restrict__ verts,
                                                   const float* __restrict__ ws,
                                                   float* __restrict__ psg){
  __shared__ float de5s[TQ][NB][5];   // 5120 B
  __shared__ float Ps2[TQ][5][48];    // 15360 B, [q][s][kj(pad48)]
  int t = threadIdx.x;
  int blockq0 = blockIdx.x * TQ;

  float* psf = &Ps2[0][0][0];
  for (int i = t; i < TQ*5*48; i += 320) psf[i] = 0.f;
  __syncthreads();

  if (t < TQ*NB){
    int ql = t >> 4;
    int n  = t & 15;
    int qg = blockq0 + ql;                       // 0..19999
    int q  = (qg >= V_CNT) ? (qg - V_CNT) : qg;
    int b0 = qg - q;                              // 0 or 10000
    int idx = nbr[qg*NB + n];
    float vx = verts[qg*3+0], vy = verts[qg*3+1], vz = verts[qg*3+2];
    const float* nv = verts + (size_t)(b0 + idx)*3;
    float dx = nv[0]-vx, dy = nv[1]-vy, dz = nv[2]-vz;
    float dd = dx*dx + dy*dy + dz*dz;
    float inv = (dd > 0.f) ? rsqrtf(dd) : 0.f;    // ref: d/max(||d||,1e-12); exact-0 -> 0
    dx *= inv; dy *= inv; dz *= inv;
    const float* fnp = ws + WS_FN;                // uniform -> scalar loads
    float s0=0.f, s1=0.f, s2=0.f, s3=0.f, s4=0.f;
    #pragma unroll
    for (int f = 0; f < 20; ++f){
      float x = fnp[f*3+0]*dx + fnp[f*3+1]*dy + fnp[f*3+2]*dz;
      float th = fast_tanh(x);
      if      (COLF[f]==0) s0 += th;
      else if (COLF[f]==1) s1 += th;
      else if (COLF[f]==2) s2 += th;
      else if (COLF[f]==3) s3 += th;
      else                 s4 += th;
    }
    de5s[ql][n][0]=s0; de5s[ql][n][1]=s1; de5s[ql][n][2]=s2;
    de5s[ql][n][3]=s3; de5s[ql][n][4]=s4;
  }
  __syncthreads();

  {
    int ql = t / 20;
    int r  = t - ql*20;
    int fidx[5];
    #pragma unroll
    for (int j = 0; j < 5; ++j) fidx[j] = FTC_d[r][j];
    int sr = fidx[0];                              // color(r) = FTC[r][0]
    float wdl[45];
    #pragma unroll
    for (int i = 0; i < 45; ++i) wdl[i] = ws[WS_WD9 + i];  // uniform
    float acc[45];
    #pragma unroll
    for (int i = 0; i < 45; ++i) acc[i] = 0.f;

    for (int n = 0; n < NB; ++n){
      float e[5];
      #pragma unroll
      for (int j = 0; j < 5; ++j) e[j] = de5s[ql][n][fidx[j]];
      #pragma unroll
      for (int k = 0; k < 9; ++k){
        float a = wdl[k*5+0]*e[0] + wdl[k*5+1]*e[1] + wdl[k*5+2]*e[2]
                + wdl[k*5+3]*e[3] + wdl[k*5+4]*e[4];
        a = fmaxf(a, 0.f);                         // relu
        #pragma unroll
        for (int j = 0; j < 5; ++j) acc[k*5+j] += a * e[j];
      }
    }
    #pragma unroll
    for (int i = 0; i < 45; ++i) atomicAdd(&Ps2[ql][sr][i], acc[i]);
  }
  __syncthreads();

  // coalesced store: psg[(qg*5+s)*48 + kj]
  for (int i = t; i < TQ*240; i += 320){
    psg[blockq0*240 + i] = psf[i];
  }
}

// ---------------------------------------------------------------------------
// Kernel 3: out[b,d,q,s] = sum_kj W45[d][kj] * Ps[q][s][kj]
//  One thread per column c = qg*5+s. B column (45 floats, contiguous, pad 48)
//  in VGPRs; W45 row uniform -> SGPR s_loads. Stores coalesced per d.
// ---------------------------------------------------------------------------
__global__ __launch_bounds__(256) void out_kernel(const float* __restrict__ ws,
                                                  const float* __restrict__ psg,
                                                  float* __restrict__ out){
  int c = blockIdx.x*256 + threadIdx.x;
  if (c >= NCOL) return;
  float breg[45];
  const float* p = psg + (size_t)c*48;
  #pragma unroll
  for (int kj = 0; kj < 45; ++kj) breg[kj] = p[kj];

  int b = (c >= 50000) ? 1 : 0;
  int local = c - b*50000;                         // q*5 + s
  float* ob = out + (size_t)b*3200000 + local;

  for (int d = 0; d < 64; ++d){
    const float* wrow = ws + WS_W45 + d*45;        // uniform -> scalar loads
    float a0=0.f, a1=0.f, a2=0.f, a3=0.f, a4=0.f;
    #pragma unroll
    for (int kj = 0; kj < 45; kj += 5){
      a0 += wrow[kj+0]*breg[kj+0];
      a1 += wrow[kj+1]*breg[kj+1];
      a2 += wrow[kj+2]*breg[kj+2];
      a3 += wrow[kj+3]*breg[kj+3];
      a4 += wrow[kj+4]*breg[kj+4];
    }
    ob[(size_t)d*50000] = ((a0+a1)+(a2+a3))+a4;
  }
}

extern "C" void kernel_launch(void* const* d_in, const int* in_sizes, int n_in,
                              void* d_out, int out_size, void* d_ws, size_t ws_size,
                              hipStream_t stream){
  const int*   nbr   = (const int*)d_in[0];
  const float* verts = (const float*)d_in[1];
  const float* W     = (const float*)d_in[2];
  const float* Wdir  = (const float*)d_in[3];
  float* out = (float*)d_out;
  float* ws  = (float*)d_ws;           // needs ~19.3 MB scratch
  float* psg = ws + WS_PSG;

  hipLaunchKernelGGL(prep_kernel, dim3(65), dim3(128), 0, stream, W, Wdir, ws);
  hipLaunchKernelGGL(fold_kernel, dim3(BQ_TOTAL/TQ), dim3(320), 0, stream, nbr, verts, ws, psg);
  hipLaunchKernelGGL(out_kernel, dim3((NCOL+255)/256), dim3(256), 0, stream, ws, psg, out);
}